// Round 7
// baseline (505.345 us; speedup 1.0000x reference)
//
#include <hip/hip_runtime.h>
#include <cstdint>
#include <cstddef>

// Problem dims (fixed by the reference)
#define MDIM 16384    // B_SZ * L
#define HDIM 1024
#define PDIM 1024
#define LSEQ 4096
#define BSZ  4
#define CHUNK 64
#define NCHUNK 64     // LSEQ / CHUNK
#define NBU  2048     // 2*PDIM (interleaved re/im)

typedef float   floatx4  __attribute__((ext_vector_type(4)));
typedef __bf16  bf16x8   __attribute__((ext_vector_type(8)));
typedef unsigned short u16;
typedef unsigned short u16x8 __attribute__((ext_vector_type(8)));

// fp32 -> bf16 round-to-nearest-even
__device__ __forceinline__ u16 f2bf(float f) {
    union { float f; uint32_t u; } v; v.f = f;
    return (u16)((v.u + 0x7fffu + ((v.u >> 16) & 1u)) >> 16);
}
__device__ __forceinline__ float bfu2f(uint32_t bits16) {
    union { float f; uint32_t u; } v; v.u = bits16 << 16; return v.f;
}
__device__ __forceinline__ bf16x8 ldfrag(const u16* p) {
    return __builtin_bit_cast(bf16x8, *(const u16x8*)p);
}
// async global->LDS, 16B per lane; LDS deposit = uniform base + lane*16
__device__ __forceinline__ void gload16(const u16* g, u16* l) {
    __builtin_amdgcn_global_load_lds(
        (const __attribute__((address_space(1))) uint32_t*)g,
        (__attribute__((address_space(3))) uint32_t*)l, 16, 0, 0);
}

// ---------------------------------------------------------------------------
// Verified 128x128 bf16 MFMA core (m97 structure): BK=64, global_load_lds
// staging, XOR-swizzled LDS (swizzle on the SOURCE address since the LDS
// deposit is fixed lane*16). A [M x KD], B [N x KD] row-major bf16.
// ---------------------------------------------------------------------------
template<int KD>
__device__ __forceinline__ void gemm_core128(
    const u16* __restrict__ A, const u16* __restrict__ B,
    int m0, int n0, u16* sA, u16* sB, floatx4 acc[4][4])
{
    const int tid  = threadIdx.x;
    const int wave = tid >> 6, lane = tid & 63;
    const int lrow = lane & 15, lq = lane >> 4;
    const int wm = (wave >> 1) * 64, wn = (wave & 1) * 64;
    const int srow   = lane >> 3;            // 0..7 row within 8-row group
    const int schunk = (lane & 7) ^ srow;    // swizzled logical 16B chunk

    const u16* aptr = A + (size_t)(m0 + wave * 32 + srow) * KD + schunk * 8;
    const u16* bptr = B + (size_t)(n0 + wave * 32 + srow) * KD + schunk * 8;
    u16* sAw = sA + wave * 32 * 64;
    u16* sBw = sB + wave * 32 * 64;

    for (int k0 = 0; k0 < KD; k0 += 64) {
        #pragma unroll
        for (int i = 0; i < 4; ++i) {
            gload16(aptr + (size_t)i * 8 * KD + k0, sAw + i * 8 * 64);
            gload16(bptr + (size_t)i * 8 * KD + k0, sBw + i * 8 * 64);
        }
        __syncthreads();
        #pragma unroll
        for (int s = 0; s < 2; ++s) {
            bf16x8 af[4], bfr[4];
            #pragma unroll
            for (int mt = 0; mt < 4; ++mt) {
                int r = wm + mt * 16 + lrow;
                af[mt] = ldfrag(sA + r * 64 + (((s * 4 + lq) ^ (r & 7)) * 8));
            }
            #pragma unroll
            for (int nt = 0; nt < 4; ++nt) {
                int r = wn + nt * 16 + lrow;
                bfr[nt] = ldfrag(sB + r * 64 + (((s * 4 + lq) ^ (r & 7)) * 8));
            }
            #pragma unroll
            for (int mt = 0; mt < 4; ++mt)
                #pragma unroll
                for (int nt = 0; nt < 4; ++nt)
                    acc[mt][nt] = __builtin_amdgcn_mfma_f32_16x16x32_bf16(
                        af[mt], bfr[nt], acc[mt][nt], 0, 0, 0);
        }
        __syncthreads();
    }
}

// ---------------------------------------------------------------------------
// Kernel: Bu = Ubf @ Bcomb^T  (M=16384, N=2048, K=1024), output bf16.
// 2048 blocks x 256 thr, XCD-banded decode; LDS repack -> 16B stores.
// ---------------------------------------------------------------------------
#define ST 136   // LDS repack row stride (u16): 272 B, 16B-aligned
__global__ __launch_bounds__(256) void gemm_bu_k(
    const u16* __restrict__ A, const u16* __restrict__ B, u16* __restrict__ O)
{
    __shared__ u16 smem[128 * ST];     // 34816 B; aliases sA|sB during K-loop
    u16* sA = smem;
    u16* sB = smem + 128 * 64;
    floatx4 acc[4][4] = {};
    const int d = blockIdx.x;
    const int xcd = d & 7, s = d >> 3;               // s: 0..255
    const int m0 = (xcd * 16 + (s >> 4)) * 128;      // m-tile band per XCD
    const int n0 = (s & 15) * 128;
    gemm_core128<HDIM>(A, B, m0, n0, sA, sB, acc);

    const int tid = threadIdx.x, wave = tid >> 6, lane = tid & 63;
    const int lrow = lane & 15, lq = lane >> 4;
    const int wm = (wave >> 1) * 64, wn = (wave & 1) * 64;

    // C tile -> LDS (row-major, stride ST)
    #pragma unroll
    for (int nt = 0; nt < 4; ++nt) {
        int col = wn + nt * 16 + lrow;
        #pragma unroll
        for (int mt = 0; mt < 4; ++mt)
            #pragma unroll
            for (int r = 0; r < 4; ++r) {
                int row = wm + mt * 16 + lq * 4 + r;
                smem[row * ST + col] = f2bf(acc[mt][nt][r]);
            }
    }
    __syncthreads();

    // coalesced store: thread t covers rows (t>>4)+16j, cols (t&15)*8..+7
    const int col = (tid & 15) * 8;
    const int rb  = tid >> 4;
    #pragma unroll
    for (int j = 0; j < 8; ++j) {
        int row = rb + j * 16;
        *(u16x8*)(O + (size_t)(m0 + row) * NBU + n0 + col) =
            *(const u16x8*)(smem + row * ST + col);
    }
}

// ---------------------------------------------------------------------------
// Kernel: out = Re(C x) + D.*u  (M=16384, N=1024, K=2048), output fp32.
// 1024 blocks x 256 thr, XCD-banded decode (round-0 verified, 86 us).
// ---------------------------------------------------------------------------
__global__ __launch_bounds__(256) void gemm_out_k(
    const u16* __restrict__ A, const u16* __restrict__ B,
    const float* __restrict__ Dv, const u16* __restrict__ Ubf,
    float* __restrict__ O)
{
    __shared__ u16 sA[128 * 64];
    __shared__ u16 sB[128 * 64];
    floatx4 acc[4][4] = {};
    const int d = blockIdx.x;
    const int xcd = d & 7, s = d >> 3;               // s: 0..127
    const int m0 = (xcd * 16 + (s >> 3)) * 128;      // m-tile band per XCD
    const int n0 = (s & 7) * 128;
    gemm_core128<NBU>(A, B, m0, n0, sA, sB, acc);

    const int tid = threadIdx.x, wave = tid >> 6, lane = tid & 63;
    const int lrow = lane & 15, lq = lane >> 4;
    const int wm = (wave >> 1) * 64, wn = (wave & 1) * 64;
    #pragma unroll
    for (int nt = 0; nt < 4; ++nt) {
        int col = n0 + wn + nt * 16 + lrow;
        float dval = Dv[col];
        #pragma unroll
        for (int mt = 0; mt < 4; ++mt)
            #pragma unroll
            for (int r = 0; r < 4; ++r) {
                int row = m0 + wm + mt * 16 + lq * 4 + r;
                size_t o = (size_t)row * HDIM + col;
                O[o] = acc[mt][nt][r] + dval * bfu2f(Ubf[o]);
            }
    }
}

// ---------------------------------------------------------------------------
// Merged prep kernel (single launch): band 0 = U->bf16 (8192 blocks),
// band 1 = Bcomb (1024 blocks), band 2 = Bcbf (1024 blocks).
// ---------------------------------------------------------------------------
__global__ __launch_bounds__(256) void prep_all(
    const float* __restrict__ U, u16* __restrict__ Ubf,
    const float* __restrict__ Bre, const float* __restrict__ Bim,
    const float* __restrict__ gamma_log, u16* __restrict__ Bcomb,
    const float* __restrict__ Cre, const float* __restrict__ Cim,
    u16* __restrict__ Bcbf)
{
    const int bid = blockIdx.x;
    if (bid < 8192) {
        size_t i = ((size_t)bid * 256 + threadIdx.x) * 8;
        float4 a = *(const float4*)(U + i);
        float4 b = *(const float4*)(U + i + 4);
        u16x8 w;
        w[0]=f2bf(a.x); w[1]=f2bf(a.y); w[2]=f2bf(a.z); w[3]=f2bf(a.w);
        w[4]=f2bf(b.x); w[5]=f2bf(b.y); w[6]=f2bf(b.z); w[7]=f2bf(b.w);
        *(u16x8*)(Ubf + i) = w;
    } else if (bid < 9216) {
        int t = (bid - 8192) * 256 + threadIdx.x;      // 0 .. 262143
        int n = t >> 7;
        int h = (t & 127) * 8;
        int p = n >> 1, sflag = n & 1;
        const float* src = (sflag ? Bim : Bre) + (size_t)p * HDIM + h;
        float g = expf(gamma_log[p]);
        float4 a = *(const float4*)src;
        float4 b = *(const float4*)(src + 4);
        u16x8 w;
        w[0]=f2bf(a.x*g); w[1]=f2bf(a.y*g); w[2]=f2bf(a.z*g); w[3]=f2bf(a.w*g);
        w[4]=f2bf(b.x*g); w[5]=f2bf(b.y*g); w[6]=f2bf(b.z*g); w[7]=f2bf(b.w*g);
        *(u16x8*)(Bcomb + (size_t)n * HDIM + h) = w;
    } else {
        int t = (bid - 9216) * 256 + threadIdx.x;      // 0 .. 262143
        int h = t >> 8;
        int k = (t & 255) * 4;
        float4 cr = *(const float4*)(Cre + (size_t)h * PDIM + k);
        float4 ci = *(const float4*)(Cim + (size_t)h * PDIM + k);
        u16x8 w;
        w[0]=f2bf(cr.x); w[1]=f2bf(-ci.x);
        w[2]=f2bf(cr.y); w[3]=f2bf(-ci.y);
        w[4]=f2bf(cr.z); w[5]=f2bf(-ci.z);
        w[6]=f2bf(cr.w); w[7]=f2bf(-ci.w);
        *(u16x8*)(Bcbf + (size_t)h * NBU + 2 * k) = w;
    }
}

// ---------------------------------------------------------------------------
// Zero the scan control block (ticket + 512 flags). Plain kernel dispatch
// (graph-capture-safe), stream-ordered after gemm_bu_k (ctl overlays the
// then-dead Bcomb head) and before scan_fused.
// ---------------------------------------------------------------------------
__global__ __launch_bounds__(256) void zero_ctl(uint32_t* __restrict__ ctl)
{
    ctl[threadIdx.x] = 0u;
    ctl[256 + threadIdx.x] = 0u;
    ctl[512 + threadIdx.x] = 0u;
    ctl[768 + threadIdx.x] = 0u;
}

// ---------------------------------------------------------------------------
// Fused single-pass scan: ticketed decoupled look-back.
// Work unit (block): one (b, chunk c, half-row). 512 blocks x 256 thr.
// Chain = (b, half): 8 chains x 64 chunks; vid = ticket, c = vid>>3 (monotone
// in ticket order -> dependencies are strictly lower tickets, resident or
// finished by construction => deadlock-free).
// ROUND-6 BUG FIX: the look-back now ALSO terminates at a chain-head
// predecessor (pv < 8). Previously, catching a chain-head in its
// flag==1 window consumed its aggregate without breaking, walked to
// pv < 0, and read garbage flags/data below the buffers -> GPU fault
// (rounds 4-6 aborts). For c==0 blocks agg E IS the inclusive prefix
// (G0 = E0), so breaking there is mathematically exact; the walk is now
// provably bounded: pv >= chain >= 0, at most c steps.
// Cross-XCD safety: flag ACQUIRE/RELEASE + data RELAXED atomics, AGENT scope.
// ---------------------------------------------------------------------------
__global__ __launch_bounds__(256) void scan_fused(
    uint32_t* __restrict__ BuC,
    const float* __restrict__ nu_log, const float* __restrict__ theta_log,
    uint32_t* __restrict__ ctl,     // [0]=ticket, [1+vid]=flag (0/1/2)
    float* __restrict__ agg,        // [512][1024] local end-states E
    float* __restrict__ inc)        // [512][1024] inclusive prefixes G
{
    __shared__ int s_vid;
    if (threadIdx.x == 0)
        s_vid = (int)atomicAdd(&ctl[0], 1u);
    __syncthreads();
    const int vid   = s_vid;
    const int c     = vid >> 3, chain = vid & 7;
    const int b     = chain >> 1, half = chain & 1;
    const int thr   = threadIdx.x;
    const int p0    = half * 512 + thr * 2;

    float nu0 = expf(nu_log[p0]),     th0 = expf(theta_log[p0]);
    float nu1 = expf(nu_log[p0 + 1]), th1 = expf(theta_log[p0 + 1]);
    float el0 = expf(-nu0), el1 = expf(-nu1);
    float lr0 = el0 * cosf(th0), li0 = el0 * sinf(th0);
    float lr1 = el1 * cosf(th1), li1 = el1 * sinf(th1);
    float e640 = expf(-nu0 * (float)CHUNK), a640 = th0 * (float)CHUNK;
    float e641 = expf(-nu1 * (float)CHUNK), a641 = th1 * (float)CHUNK;
    float Lr0 = e640 * cosf(a640), Li0 = e640 * sinf(a640);
    float Lr1 = e641 * cosf(a641), Li1 = e641 * sinf(a641);

    uint32_t* base = BuC + (size_t)(b * LSEQ + c * CHUNK) * PDIM + p0;

    // ---- sweep 1: local end-state E (from zero state)
    float xr0 = 0.f, xi0 = 0.f, xr1 = 0.f, xi1 = 0.f;
    #pragma unroll 8
    for (int t = 0; t < CHUNK; ++t) {
        uint2 v = *(const uint2*)(base + (size_t)t * PDIM);
        float br0 = bfu2f(v.x & 0xffffu), bi0 = bfu2f(v.x >> 16);
        float br1 = bfu2f(v.y & 0xffffu), bi1 = bfu2f(v.y >> 16);
        float nr0 = fmaf(lr0, xr0, fmaf(-li0, xi0, br0));
        float ni0 = fmaf(lr0, xi0, fmaf(li0, xr0, bi0));
        float nr1 = fmaf(lr1, xr1, fmaf(-li1, xi1, br1));
        float ni1 = fmaf(lr1, xi1, fmaf(li1, xr1, bi1));
        xr0 = nr0; xi0 = ni0; xr1 = nr1; xi1 = ni1;
    }

    // ---- publish aggregate E (flag=1)
    {
        float* ag = agg + (size_t)vid * 1024 + thr * 4;
        __hip_atomic_store(&ag[0], xr0, __ATOMIC_RELAXED, __HIP_MEMORY_SCOPE_AGENT);
        __hip_atomic_store(&ag[1], xi0, __ATOMIC_RELAXED, __HIP_MEMORY_SCOPE_AGENT);
        __hip_atomic_store(&ag[2], xr1, __ATOMIC_RELAXED, __HIP_MEMORY_SCOPE_AGENT);
        __hip_atomic_store(&ag[3], xi1, __ATOMIC_RELAXED, __HIP_MEMORY_SCOPE_AGENT);
    }
    __syncthreads();
    if (threadIdx.x == 0)
        __hip_atomic_store(&ctl[1 + vid], 1u, __ATOMIC_RELEASE, __HIP_MEMORY_SCOPE_AGENT);

    // ---- look-back: carry = X_end(c-1) = sum_d L64^{d-1} * E_{c-d},
    //      terminated by an inclusive G (flag=2) OR a chain-head (pv<8,
    //      whose E == G). Bounded: pv >= chain >= 0.
    float cr0 = 0.f, ci0 = 0.f, cr1 = 0.f, ci1 = 0.f;
    if (c > 0) {
        float pr0 = 1.f, pi0 = 0.f, pr1 = 1.f, pi1 = 0.f;   // L64^{d-1}
        int d = 1;
        while (true) {
            const int pv = vid - 8 * d;
            uint32_t f;
            while ((f = __hip_atomic_load(&ctl[1 + pv], __ATOMIC_ACQUIRE,
                                          __HIP_MEMORY_SCOPE_AGENT)) == 0u)
                __builtin_amdgcn_s_sleep(1);
            const float* src = (f == 2u ? inc : agg) + (size_t)pv * 1024 + thr * 4;
            float vr0 = __hip_atomic_load(&src[0], __ATOMIC_RELAXED, __HIP_MEMORY_SCOPE_AGENT);
            float vi0 = __hip_atomic_load(&src[1], __ATOMIC_RELAXED, __HIP_MEMORY_SCOPE_AGENT);
            float vr1 = __hip_atomic_load(&src[2], __ATOMIC_RELAXED, __HIP_MEMORY_SCOPE_AGENT);
            float vi1 = __hip_atomic_load(&src[3], __ATOMIC_RELAXED, __HIP_MEMORY_SCOPE_AGENT);
            cr0 += pr0 * vr0 - pi0 * vi0;  ci0 += pr0 * vi0 + pi0 * vr0;
            cr1 += pr1 * vr1 - pi1 * vi1;  ci1 += pr1 * vi1 + pi1 * vr1;
            if (f == 2u || pv < 8) break;   // FIX: chain-head agg == inclusive
            float t0 = pr0 * Lr0 - pi0 * Li0; pi0 = pr0 * Li0 + pi0 * Lr0; pr0 = t0;
            float t1 = pr1 * Lr1 - pi1 * Li1; pi1 = pr1 * Li1 + pi1 * Lr1; pr1 = t1;
            ++d;
        }
    }

    // ---- publish inclusive G_c = L64 * carry + E (flag=2)
    {
        float gr0 = fmaf(Lr0, cr0, fmaf(-Li0, ci0, xr0));
        float gi0 = fmaf(Lr0, ci0, fmaf(Li0, cr0, xi0));
        float gr1 = fmaf(Lr1, cr1, fmaf(-Li1, ci1, xr1));
        float gi1 = fmaf(Lr1, ci1, fmaf(Li1, cr1, xi1));
        float* ic = inc + (size_t)vid * 1024 + thr * 4;
        __hip_atomic_store(&ic[0], gr0, __ATOMIC_RELAXED, __HIP_MEMORY_SCOPE_AGENT);
        __hip_atomic_store(&ic[1], gi0, __ATOMIC_RELAXED, __HIP_MEMORY_SCOPE_AGENT);
        __hip_atomic_store(&ic[2], gr1, __ATOMIC_RELAXED, __HIP_MEMORY_SCOPE_AGENT);
        __hip_atomic_store(&ic[3], gi1, __ATOMIC_RELAXED, __HIP_MEMORY_SCOPE_AGENT);
    }
    __syncthreads();
    if (threadIdx.x == 0)
        __hip_atomic_store(&ctl[1 + vid], 2u, __ATOMIC_RELEASE, __HIP_MEMORY_SCOPE_AGENT);

    // ---- sweep 2: rescan chunk from carry, write x in place (bf16 packed)
    xr0 = cr0; xi0 = ci0; xr1 = cr1; xi1 = ci1;
    #pragma unroll 8
    for (int t = 0; t < CHUNK; ++t) {
        uint32_t* q = base + (size_t)t * PDIM;
        uint2 v = *(const uint2*)q;
        float br0 = bfu2f(v.x & 0xffffu), bi0 = bfu2f(v.x >> 16);
        float br1 = bfu2f(v.y & 0xffffu), bi1 = bfu2f(v.y >> 16);
        float nr0 = fmaf(lr0, xr0, fmaf(-li0, xi0, br0));
        float ni0 = fmaf(lr0, xi0, fmaf(li0, xr0, bi0));
        float nr1 = fmaf(lr1, xr1, fmaf(-li1, xi1, br1));
        float ni1 = fmaf(lr1, xi1, fmaf(li1, xr1, bi1));
        xr0 = nr0; xi0 = ni0; xr1 = nr1; xi1 = ni1;
        uint2 o;
        o.x = (uint32_t)f2bf(xr0) | ((uint32_t)f2bf(xi0) << 16);
        o.y = (uint32_t)f2bf(xr1) | ((uint32_t)f2bf(xi1) << 16);
        *(uint2*)q = o;
    }
}

// ---------------------------------------------------------------------------
extern "C" void kernel_launch(void* const* d_in, const int* in_sizes, int n_in,
                              void* d_out, int out_size, void* d_ws, size_t ws_size,
                              hipStream_t stream)
{
    (void)in_sizes; (void)n_in; (void)out_size; (void)ws_size;
    const float* U         = (const float*)d_in[0];
    const float* nu_log    = (const float*)d_in[1];
    const float* theta_log = (const float*)d_in[2];
    const float* B_re      = (const float*)d_in[3];
    const float* B_im      = (const float*)d_in[4];
    const float* C_re      = (const float*)d_in[5];
    const float* C_im      = (const float*)d_in[6];
    const float* Dv        = (const float*)d_in[7];
    const float* gamma_log = (const float*)d_in[8];
    float* out = (float*)d_out;

    // workspace layout (bytes), 256B aligned, total exactly 108 MB
    char* ws = (char*)d_ws;
    u16*      BuC   = (u16*)ws;                                   // 64 MB
    u16*      Ubf   = (u16*)(ws + (size_t)64 * 1024 * 1024);      // 32 MB
    u16*      Bcomb = (u16*)(ws + (size_t)96 * 1024 * 1024);      // 4 MB
    u16*      Bcbf  = (u16*)(ws + (size_t)100 * 1024 * 1024);     // 4 MB
    float*    agg   = (float*)(ws + (size_t)104 * 1024 * 1024);   // 2 MB
    float*    inc   = (float*)(ws + (size_t)106 * 1024 * 1024);   // 2 MB
    // ctl overlays the head of Bcomb (dead after gemm_bu_k; rewritten by
    // prep_all on the next replay before gemm_bu_k reads it again)
    uint32_t* ctl   = (uint32_t*)(ws + (size_t)96 * 1024 * 1024); // 4 KB

    prep_all<<<8192 + 1024 + 1024, 256, 0, stream>>>(
        U, Ubf, B_re, B_im, gamma_log, Bcomb, C_re, C_im, Bcbf);

    gemm_bu_k<<<2048, 256, 0, stream>>>(Ubf, Bcomb, BuC);

    zero_ctl<<<1, 256, 0, stream>>>(ctl);   // ticket + flags, per replay
    scan_fused<<<BSZ * NCHUNK * 2, 256, 0, stream>>>(
        (uint32_t*)BuC, nu_log, theta_log, ctl, agg, inc);

    gemm_out_k<<<1024, 256, 0, stream>>>(BuC, Bcbf, Dv, Ubf, out);
}